// Round 1
// baseline (6587.126 us; speedup 1.0000x reference)
//
#include <hip/hip_runtime.h>
#include <float.h>

// EdgeConv: B=4, N=4096, Fin=64, Fout=64, K=20
// out[b,n,o] = u[b,n,o] + max_{m in knn20(n)} v[b,m,o]
//   u = x . (W1 - W2)^T + bias ; v = x . W2^T ; W1=W[:, :64], W2=W[:, 64:]
// knn key: ||x_m||^2 - 2 x_n.x_m  (row-constant ||x_n||^2 dropped), self excluded.

constexpr int Bb = 4, Nn = 4096, Ff = 64, Kk = 20;
constexpr int RT = 4;  // rows (n) per block

__global__ __launch_bounds__(256) void uv_kernel(
    const float* __restrict__ x, const float* __restrict__ W,
    const float* __restrict__ bvec, float* __restrict__ u,
    float* __restrict__ v, float* __restrict__ sq) {
  const int t = threadIdx.x;
  const int bn0 = blockIdx.x * RT;  // flat (b*N+n) base
  __shared__ __align__(16) float4 xs4[RT][Ff / 4];
  ((float*)xs4)[t] = x[bn0 * Ff + t];  // 256 consecutive floats, coalesced
  __syncthreads();
  const int r = t >> 6, o = t & 63;  // wave r handles row r, lane = output channel
  // squared norm of row r via wave butterfly
  float xv1 = ((const float*)xs4[r])[o];
  float s = xv1 * xv1;
  #pragma unroll
  for (int d = 32; d; d >>= 1) s += __shfl_xor(s, d, 64);
  if (o == 0) sq[bn0 + r] = s;
  // u, v for (row r, channel o)
  float ua = 0.f, va = 0.f;
  const float4* w1 = (const float4*)(W + o * 2 * Ff);
  const float4* w2 = (const float4*)(W + o * 2 * Ff + Ff);
  #pragma unroll
  for (int c = 0; c < Ff / 4; c++) {
    float4 xv = xs4[r][c];
    float4 a = w1[c];
    float4 b2 = w2[c];
    ua += xv.x * (a.x - b2.x) + xv.y * (a.y - b2.y) + xv.z * (a.z - b2.z) +
          xv.w * (a.w - b2.w);
    va += xv.x * b2.x + xv.y * b2.y + xv.z * b2.z + xv.w * b2.w;
  }
  u[(bn0 + r) * Ff + o] = ua + bvec[o];
  v[(bn0 + r) * Ff + o] = va;
}

__global__ __launch_bounds__(256) void knn_kernel(
    const float* __restrict__ x, const float* __restrict__ sq,
    const float* __restrict__ u, const float* __restrict__ v,
    float* __restrict__ out) {
  const int t = threadIdx.x;
  const int lane = t & 63, wid = t >> 6;
  const int bn0 = blockIdx.x * RT;
  const int b = bn0 >> 12;        // / N
  const int n0 = bn0 & (Nn - 1);  // % N
  const float* xb = x + b * Nn * Ff;
  const float* sqb = sq + b * Nn;

  __shared__ __align__(16) float4 xs4[RT][Ff / 4];
  ((float*)xs4)[t] = xb[n0 * Ff + t];
  __syncthreads();

  // --- distance compute: thread t owns m = t + 256*j, j in [0,16), 4 rows ---
  float dd[RT][16];
  #pragma unroll
  for (int jb = 0; jb < 4; jb++) {
    float a[4][RT];
    #pragma unroll
    for (int q = 0; q < 4; q++)
      #pragma unroll
      for (int r = 0; r < RT; r++) a[q][r] = 0.f;
    const float4* xm0 = (const float4*)(xb + (t + 256 * (4 * jb + 0)) * Ff);
    const float4* xm1 = (const float4*)(xb + (t + 256 * (4 * jb + 1)) * Ff);
    const float4* xm2 = (const float4*)(xb + (t + 256 * (4 * jb + 2)) * Ff);
    const float4* xm3 = (const float4*)(xb + (t + 256 * (4 * jb + 3)) * Ff);
    #pragma unroll
    for (int c = 0; c < Ff / 4; c++) {
      float4 m0 = xm0[c], m1 = xm1[c], m2 = xm2[c], m3 = xm3[c];
      #pragma unroll
      for (int r = 0; r < RT; r++) {
        float4 p = xs4[r][c];  // wave-uniform LDS broadcast
        a[0][r] += m0.x * p.x + m0.y * p.y + m0.z * p.z + m0.w * p.w;
        a[1][r] += m1.x * p.x + m1.y * p.y + m1.z * p.z + m1.w * p.w;
        a[2][r] += m2.x * p.x + m2.y * p.y + m2.z * p.z + m2.w * p.w;
        a[3][r] += m3.x * p.x + m3.y * p.y + m3.z * p.z + m3.w * p.w;
      }
    }
    #pragma unroll
    for (int q = 0; q < 4; q++) {
      int j = 4 * jb + q;
      int m = t + 256 * j;
      float sm = sqb[m];
      #pragma unroll
      for (int r = 0; r < RT; r++)
        dd[r][j] = (m == n0 + r) ? FLT_MAX : fmaf(-2.f, a[q][r], sm);
    }
  }

  // --- local argmin state per row ---
  float lmin[RT];
  int lj[RT];
  #pragma unroll
  for (int r = 0; r < RT; r++) {
    float nm = FLT_MAX;
    int nj = 0;
    #pragma unroll
    for (int j = 0; j < 16; j++)
      if (dd[r][j] < nm) { nm = dd[r][j]; nj = j; }
    lmin[r] = nm;
    lj[r] = nj;
  }

  __shared__ float waveMin[4][RT];
  __shared__ int winnerWave[RT];
  __shared__ int knnIdx[RT][Kk];

  // --- 20 exact min-extractions ---
  for (int it = 0; it < Kk; it++) {
    float wmin[RT];
    #pragma unroll
    for (int r = 0; r < RT; r++) {
      float wv = lmin[r];
      #pragma unroll
      for (int d = 32; d; d >>= 1) wv = fminf(wv, __shfl_xor(wv, d, 64));
      wmin[r] = wv;
    }
    if (lane == 0) {
      #pragma unroll
      for (int r = 0; r < RT; r++) waveMin[wid][r] = wmin[r];
    }
    __syncthreads();
    if (t < RT) {
      float bm = waveMin[0][t];
      int ww = 0;
      #pragma unroll
      for (int w = 1; w < 4; w++)
        if (waveMin[w][t] < bm) { bm = waveMin[w][t]; ww = w; }
      winnerWave[t] = ww;
    }
    __syncthreads();
    #pragma unroll
    for (int r = 0; r < RT; r++) {
      int ww = winnerWave[r];
      if (wid == ww) {  // wave-uniform branch
        unsigned long long mask = __ballot(lmin[r] == wmin[r]);
        int src = __builtin_ctzll(mask);
        int jw = __shfl(lj[r], src, 64);
        if (lane == 0) knnIdx[r][it] = ww * 64 + src + 256 * jw;
        if (lane == src) {
          #pragma unroll
          for (int j = 0; j < 16; j++)
            if (j == jw) dd[r][j] = FLT_MAX;
          float nm = FLT_MAX;
          int nj = 0;
          #pragma unroll
          for (int j = 0; j < 16; j++)
            if (dd[r][j] < nm) { nm = dd[r][j]; nj = j; }
          lmin[r] = nm;
          lj[r] = nj;
        }
      }
    }
  }
  __syncthreads();

  // --- output: wave r handles row r; lane = channel o ---
  {
    const int r = wid, o = lane;
    float acc = -FLT_MAX;
    #pragma unroll
    for (int j = 0; j < Kk; j++) {
      int m = knnIdx[r][j];
      acc = fmaxf(acc, v[(b * Nn + m) * Ff + o]);
    }
    out[(bn0 + r) * Ff + o] = u[(bn0 + r) * Ff + o] + acc;
  }
}

extern "C" void kernel_launch(void* const* d_in, const int* in_sizes, int n_in,
                              void* d_out, int out_size, void* d_ws,
                              size_t ws_size, hipStream_t stream) {
  const float* x = (const float*)d_in[0];
  const float* W = (const float*)d_in[1];
  const float* bvec = (const float*)d_in[2];
  // d_in[3] is k (device scalar) — fixed to 20 per problem spec.
  float* u = (float*)d_ws;
  float* v = u + (size_t)Bb * Nn * Ff;
  float* sq = v + (size_t)Bb * Nn * Ff;
  float* out = (float*)d_out;

  uv_kernel<<<Bb * Nn / RT, 256, 0, stream>>>(x, W, bvec, u, v, sq);
  knn_kernel<<<Bb * Nn / RT, 256, 0, stream>>>(x, sq, u, v, out);
}

// Round 2
// 527.019 us; speedup vs baseline: 12.4988x; 12.4988x over previous
//
#include <hip/hip_runtime.h>
#include <float.h>

// EdgeConv: B=4, N=4096, Fin=64, Fout=64, K=20
// out[b,n,o] = u[b,n,o] + max_{m in knn20(n)} v[b,m,o]
//   u = x.(W1-W2)^T + bias ; v = x.W2^T
// knn on full squared distance d = sq[n] + sq[m] - 2 x_n.x_m (>=0), self excluded.
//
// knn_kernel design (R2): no spillable per-thread arrays.
//  - x_m staged via LDS tiles (64 rows, padded stride 17 float4s)
//  - channel-quarter split: lane group g = l>>4 owns channels [16g,16g+16);
//    wave w owns tile rows [16w,16w+16); 2x shfl_xor combines quarters.
//  - distance -> monotone u16 key (f32 bits >> 15), stored to LDS keys[r][m];
//    lane's kept row r == its channel group g.
//  - selection: wave w bisects row w's u16 key space (no barriers, no dynamic
//    register indexing), collects <=64 candidate indices, recomputes exact
//    fp32 distance per candidate, then 20 exact min-extractions via u64
//    (dbits<<32|m) shuffle butterflies fused with coalesced v-gather + max.

constexpr int Bb = 4, Nn = 4096, Ff = 64, Kk = 20;
constexpr int RT = 4;    // rows per block (= waves per block)
constexpr int MT = 64;   // m-tile rows
constexpr int TPAD = 17; // float4 stride per tile row (68 dwords, bank spread)
constexpr int NTILE = Nn / MT;
constexpr int CCAP = 64; // candidate capacity per row

__global__ __launch_bounds__(256) void uv_kernel(
    const float* __restrict__ x, const float* __restrict__ W,
    const float* __restrict__ bvec, float* __restrict__ u,
    float* __restrict__ v, float* __restrict__ sq) {
  const int t = threadIdx.x;
  const int bn0 = blockIdx.x * RT;
  __shared__ __align__(16) float4 xs4[RT][Ff / 4];
  ((float*)xs4)[t] = x[bn0 * Ff + t];
  __syncthreads();
  const int r = t >> 6, o = t & 63;
  float xv1 = ((const float*)xs4[r])[o];
  float s = xv1 * xv1;
  #pragma unroll
  for (int d = 32; d; d >>= 1) s += __shfl_xor(s, d, 64);
  if (o == 0) sq[bn0 + r] = s;
  float ua = 0.f, va = 0.f;
  const float4* w1 = (const float4*)(W + o * 2 * Ff);
  const float4* w2 = (const float4*)(W + o * 2 * Ff + Ff);
  #pragma unroll
  for (int c = 0; c < Ff / 4; c++) {
    float4 xv = xs4[r][c];
    float4 a = w1[c];
    float4 b2 = w2[c];
    ua += xv.x * (a.x - b2.x) + xv.y * (a.y - b2.y) + xv.z * (a.z - b2.z) +
          xv.w * (a.w - b2.w);
    va += xv.x * b2.x + xv.y * b2.y + xv.z * b2.z + xv.w * b2.w;
  }
  u[(bn0 + r) * Ff + o] = ua + bvec[o];
  v[(bn0 + r) * Ff + o] = va;
}

__global__ __launch_bounds__(256) void knn_kernel(
    const float* __restrict__ x, const float* __restrict__ sq,
    const float* __restrict__ u, const float* __restrict__ v,
    float* __restrict__ out) {
  __shared__ __align__(16) float4 tileS[MT * TPAD];          // 17408 B
  __shared__ __align__(16) unsigned short keysS[RT * Nn];    // 32768 B
  __shared__ int candS[RT * CCAP];                           // 1024 B
  __shared__ int ccntS[RT];

  const int t = threadIdx.x;
  const int l = t & 63, w = t >> 6;
  const int q = l & 15, g = l >> 4;
  const int bn0 = blockIdx.x * RT;
  const int b = bn0 >> 12;
  const int n0 = bn0 & (Nn - 1);
  const float4* xb4 = (const float4*)(x + (size_t)b * Nn * Ff);
  const float* sqb = sq + b * Nn;

  if (t < RT) ccntS[t] = 0;  // ordered by first __syncthreads below

  // x_n channel-quarters in registers: rows n0+r, channels [16g, 16g+16)
  float4 xnq[RT][4];
  #pragma unroll
  for (int r = 0; r < RT; r++)
    #pragma unroll
    for (int c = 0; c < 4; c++) xnq[r][c] = xb4[(n0 + r) * 16 + 4 * g + c];
  const float sn = sqb[n0 + g];  // this lane keeps row r = g
  const int selfm = n0 + g;

  // ---- distance pass over 64 tiles ----
  for (int T = 0; T < NTILE; ++T) {
    __syncthreads();
    #pragma unroll
    for (int i = 0; i < 4; i++) {
      int f = t + 256 * i;  // flat float4 index in tile
      tileS[(f >> 4) * TPAD + (f & 15)] = xb4[T * 1024 + f];
    }
    __syncthreads();
    const int mrow = 16 * w + q;
    const float4* xmp = &tileS[mrow * TPAD + 4 * g];
    float4 xm0 = xmp[0], xm1 = xmp[1], xm2 = xmp[2], xm3 = xmp[3];
    float dot[RT];
    #pragma unroll
    for (int r = 0; r < RT; r++) {
      float4 a0 = xnq[r][0], a1 = xnq[r][1], a2 = xnq[r][2], a3 = xnq[r][3];
      dot[r] = a0.x * xm0.x + a0.y * xm0.y + a0.z * xm0.z + a0.w * xm0.w +
               a1.x * xm1.x + a1.y * xm1.y + a1.z * xm1.z + a1.w * xm1.w +
               a2.x * xm2.x + a2.y * xm2.y + a2.z * xm2.z + a2.w * xm2.w +
               a3.x * xm3.x + a3.y * xm3.y + a3.z * xm3.z + a3.w * xm3.w;
    }
    #pragma unroll
    for (int r = 0; r < RT; r++) {
      dot[r] += __shfl_xor(dot[r], 16, 64);
      dot[r] += __shfl_xor(dot[r], 32, 64);
    }
    float dg = (g == 0) ? dot[0] : (g == 1) ? dot[1] : (g == 2) ? dot[2] : dot[3];
    int m = T * MT + mrow;
    float d = fmaxf(fmaf(-2.f, dg, sqb[m] + sn), 0.f);
    unsigned int key = __float_as_uint(d) >> 15;  // monotone for d>=0
    if (m == selfm) key = 0xFFFFu;
    keysS[g * Nn + m] = (unsigned short)key;
  }
  __syncthreads();

  // ---- per-wave bisection on row w's u16 keys (lane owns m in [64l,64l+64)) ----
  const unsigned int* kp = (const unsigned int*)&keysS[w * Nn];  // 2048 uints
  int lo = -1, hi = 65535, cntHi = Nn;
  while (cntHi > 48 && hi - lo > 1) {
    int mid = (lo + hi) >> 1;
    unsigned int midu = (unsigned int)mid;
    int c = 0;
    #pragma unroll
    for (int cc = 0; cc < 8; ++cc) {
      int rc = (cc + l) & 7;  // rotation: spreads banks
      uint4 k4 = *(const uint4*)(kp + l * 32 + rc * 4);
      c += ((k4.x & 0xffffu) <= midu) + ((k4.x >> 16) <= midu);
      c += ((k4.y & 0xffffu) <= midu) + ((k4.y >> 16) <= midu);
      c += ((k4.z & 0xffffu) <= midu) + ((k4.z >> 16) <= midu);
      c += ((k4.w & 0xffffu) <= midu) + ((k4.w >> 16) <= midu);
    }
    #pragma unroll
    for (int d2 = 1; d2 < 64; d2 <<= 1) c += __shfl_xor(c, d2, 64);
    if (c >= Kk) { hi = mid; cntHi = c; } else { lo = mid; }
  }

  // ---- collect candidate indices (key <= hi) ----
  {
    unsigned int hu = (unsigned int)hi;
    #pragma unroll
    for (int cc = 0; cc < 8; ++cc) {
      int rc = (cc + l) & 7;
      uint4 k4 = *(const uint4*)(kp + l * 32 + rc * 4);
      unsigned int ks[4] = {k4.x, k4.y, k4.z, k4.w};
      #pragma unroll
      for (int uu = 0; uu < 4; ++uu) {
        #pragma unroll
        for (int h = 0; h < 2; ++h) {
          unsigned int kv = h ? (ks[uu] >> 16) : (ks[uu] & 0xffffu);
          if (kv <= hu) {
            int slot = atomicAdd(&ccntS[w], 1);
            if (slot < CCAP) candS[w * CCAP + slot] = l * 64 + (rc * 4 + uu) * 2 + h;
          }
        }
      }
    }
  }
  __syncthreads();

  // ---- finalize: wave w = row n0+w; lane = candidate slot AND channel ----
  const int n = n0 + w;
  const int C = min(cntHi, CCAP);
  unsigned long long key64 = ~0ULL;
  if (l < C) {
    int mI = candS[w * CCAP + l];
    const float4* xmf = xb4 + mI * 16;
    float ds = 0.f;
    #pragma unroll
    for (int c = 0; c < 16; c++) {
      float4 a = xb4[n * 16 + c];  // wave-uniform
      float4 bb = xmf[c];
      float dx = a.x - bb.x, dy = a.y - bb.y, dz = a.z - bb.z, dw2 = a.w - bb.w;
      ds += dx * dx + dy * dy + dz * dz + dw2 * dw2;
    }
    key64 = ((unsigned long long)__float_as_uint(ds) << 32) | (unsigned int)mI;
  }
  float vmax = -FLT_MAX;
  const float* vb = v + (size_t)b * Nn * Ff;
  #pragma unroll
  for (int it = 0; it < Kk; ++it) {
    unsigned long long kmin = key64;
    #pragma unroll
    for (int d2 = 1; d2 < 64; d2 <<= 1) {
      unsigned long long o =
          (unsigned long long)__shfl_xor((long long)kmin, d2, 64);
      kmin = (o < kmin) ? o : kmin;
    }
    int mI = (int)(kmin & 0xffffffffu);
    vmax = fmaxf(vmax, vb[mI * 64 + l]);
    if (key64 == kmin) key64 = ~0ULL;
  }
  const size_t oidx = (size_t)(bn0 + w) * 64 + l;
  out[oidx] = u[oidx] + vmax;
}

extern "C" void kernel_launch(void* const* d_in, const int* in_sizes, int n_in,
                              void* d_out, int out_size, void* d_ws,
                              size_t ws_size, hipStream_t stream) {
  const float* x = (const float*)d_in[0];
  const float* W = (const float*)d_in[1];
  const float* bvec = (const float*)d_in[2];
  // d_in[3] is k (device scalar) — fixed to 20 per problem spec.
  float* u = (float*)d_ws;
  float* v = u + (size_t)Bb * Nn * Ff;
  float* sq = v + (size_t)Bb * Nn * Ff;
  float* out = (float*)d_out;

  uv_kernel<<<Bb * Nn / RT, 256, 0, stream>>>(x, W, bvec, u, v, sq);
  knn_kernel<<<Bb * Nn / RT, 256, 0, stream>>>(x, sq, u, v, out);
}